// Round 1
// baseline (1754.048 us; speedup 1.0000x reference)
//
#include <hip/hip_runtime.h>

// LSTM: B=2048, T=4096, IN=1, H=8, OUT=1, two layers + linear head. fp32.
// Decomposition: 32 lanes per sequence (lane = gate row l in [0,32)),
// 2 sequences per wave64, 8 sequences per 256-thread block -> 256 blocks,
// 1024 waves total = 1 wave/SIMD on 256 CUs.
// Layers software-pipelined: iteration t computes L0(t) and L1(t-1) (both
// read h1(t-1)) -> two independent dep chains per iteration.

constexpr int Bsz = 2048;
constexpr int Tsz = 4096;

__device__ __forceinline__ float sig_from_scaled(float zs) {
    // zs = -log2(e) * z  (scaling pre-folded into weights); returns sigmoid(z)
    float e = __builtin_amdgcn_exp2f(zs);
    return __builtin_amdgcn_rcpf(1.0f + e);
}

__device__ __forceinline__ float tanh_fast(float c) {
    // tanh(c) = 2*sigmoid(2c) - 1
    const float N2L2E = -2.8853900817779268f; // -2*log2(e)
    float e = __builtin_amdgcn_exp2f(c * N2L2E);
    return fmaf(2.0f, __builtin_amdgcn_rcpf(1.0f + e), -1.0f);
}

__global__ void __launch_bounds__(256) lstm2_fused(
    const float* __restrict__ x,      // [B, T]   (IN == 1)
    const float* __restrict__ Wih0,   // [32, 1]
    const float* __restrict__ Whh0,   // [32, 8]
    const float* __restrict__ bih0,   // [32]
    const float* __restrict__ bhh0,   // [32]
    const float* __restrict__ Wih1,   // [32, 8]
    const float* __restrict__ Whh1,   // [32, 8]
    const float* __restrict__ bih1,   // [32]
    const float* __restrict__ bhh1,   // [32]
    const float* __restrict__ Wlin,   // [1, 8]
    const float* __restrict__ blin,   // [1]
    float* __restrict__ out)          // [B, T]
{
    const int tid = threadIdx.x;
    const int l   = tid & 31;          // gate row (PyTorch order: i f g o, 8 each)
    const int j   = l & 7;             // hidden unit this lane's cell update owns
    const int gid = l >> 3;            // 0=i 1=f 2=g 3=o
    const int seg = tid & 32;          // wave-half base lane (0 or 32)
    const int seq = blockIdx.x * 8 + (tid >> 5);

    const float NL2E = -1.4426950408889634f;     // -log2(e)
    const float ws   = (gid == 2) ? 2.0f * NL2E : NL2E;  // g-rows: tanh via 2*sig(2z)-1
    const float sA   = (gid == 2) ? 2.0f : 1.0f;
    const float oA   = (gid == 2) ? -1.0f : 0.0f;

    // Per-lane weight row, pre-scaled so the activation is uniform across lanes.
    float w0[8], w1x[8], w1h[8], wl[8];
#pragma unroll
    for (int k = 0; k < 8; ++k) {
        w0[k]  = Whh0[l * 8 + k] * ws;
        w1x[k] = Wih1[l * 8 + k] * ws;
        w1h[k] = Whh1[l * 8 + k] * ws;
        wl[k]  = Wlin[k];
    }
    const float wx0   = Wih0[l] * ws;
    const float bias0 = (bih0[l] + bhh0[l]) * ws;
    const float bias1 = (bih1[l] + bhh1[l]) * ws;
    const float bl    = blin[0];

    const float* __restrict__ xp = x + (size_t)seq * Tsz;
    float* __restrict__ op       = out + (size_t)seq * Tsz;

    float h1b[8], h2b[8];          // broadcast copies of h1 / h2 (all 8 units)
#pragma unroll
    for (int k = 0; k < 8; ++k) { h1b[k] = 0.0f; h2b[k] = 0.0f; }
    float c1 = 0.0f, c2 = 0.0f;    // cell state for unit j (replicated x4)

    // ---- peel: layer0 @ t=0 (h1 = 0, matvec vanishes) ----
    {
        float z0 = fmaf(xp[0], wx0, bias0);
        float g0 = fmaf(sig_from_scaled(z0), sA, oA);
        float i0 = __shfl(g0, seg + j,      64);
        float f0 = __shfl(g0, seg + j + 8,  64);
        float gg = __shfl(g0, seg + j + 16, 64);
        float o0 = __shfl(g0, seg + j + 24, 64);
        c1 = fmaf(f0, c1, i0 * gg);
        float h1j = o0 * tanh_fast(c1);
#pragma unroll
        for (int k = 0; k < 8; ++k) h1b[k] = __shfl(h1j, seg + k, 64);
    }

    float xnext = xp[1];
    for (int t = 1; t < Tsz; ++t) {
        const float xt = xnext;
        int tn = t + 1; tn = (tn < Tsz) ? tn : (Tsz - 1);
        xnext = xp[tn];                       // prefetch next step's input

        // Two independent chains: L0(t) and L1(t-1); both read h1b = h1(t-1).
        float z0 = fmaf(xt, wx0, bias0);
        float z1 = bias1;
#pragma unroll
        for (int k = 0; k < 8; ++k) {
            z0 = fmaf(h1b[k], w0[k],  z0);
            z1 = fmaf(h1b[k], w1x[k], z1);
        }
#pragma unroll
        for (int k = 0; k < 8; ++k) z1 = fmaf(h2b[k], w1h[k], z1);

        float g0 = fmaf(sig_from_scaled(z0), sA, oA);
        float g1 = fmaf(sig_from_scaled(z1), sA, oA);

        float i0  = __shfl(g0, seg + j,      64);
        float f0  = __shfl(g0, seg + j + 8,  64);
        float gg0 = __shfl(g0, seg + j + 16, 64);
        float o0  = __shfl(g0, seg + j + 24, 64);
        float i1  = __shfl(g1, seg + j,      64);
        float f1  = __shfl(g1, seg + j + 8,  64);
        float gg1 = __shfl(g1, seg + j + 16, 64);
        float o1  = __shfl(g1, seg + j + 24, 64);

        c1 = fmaf(f0, c1, i0 * gg0);
        c2 = fmaf(f1, c2, i1 * gg1);
        float h1j = o0 * tanh_fast(c1);
        float h2j = o1 * tanh_fast(c2);
#pragma unroll
        for (int k = 0; k < 8; ++k) h1b[k] = __shfl(h1j, seg + k, 64);
#pragma unroll
        for (int k = 0; k < 8; ++k) h2b[k] = __shfl(h2j, seg + k, 64);

        float p = bl;
#pragma unroll
        for (int k = 0; k < 8; ++k) p = fmaf(h2b[k], wl[k], p);
        if (l == 0) op[t - 1] = p;
    }

    // ---- epilogue: layer1 @ T-1 ----
    {
        float z1 = bias1;
#pragma unroll
        for (int k = 0; k < 8; ++k) z1 = fmaf(h1b[k], w1x[k], z1);
#pragma unroll
        for (int k = 0; k < 8; ++k) z1 = fmaf(h2b[k], w1h[k], z1);
        float g1  = fmaf(sig_from_scaled(z1), sA, oA);
        float i1  = __shfl(g1, seg + j,      64);
        float f1  = __shfl(g1, seg + j + 8,  64);
        float gg1 = __shfl(g1, seg + j + 16, 64);
        float o1  = __shfl(g1, seg + j + 24, 64);
        c2 = fmaf(f1, c2, i1 * gg1);
        float h2j = o1 * tanh_fast(c2);
#pragma unroll
        for (int k = 0; k < 8; ++k) h2b[k] = __shfl(h2j, seg + k, 64);
        float p = bl;
#pragma unroll
        for (int k = 0; k < 8; ++k) p = fmaf(h2b[k], wl[k], p);
        if (l == 0) op[Tsz - 1] = p;
    }
}

extern "C" void kernel_launch(void* const* d_in, const int* in_sizes, int n_in,
                              void* d_out, int out_size, void* d_ws, size_t ws_size,
                              hipStream_t stream) {
    const float* x    = (const float*)d_in[0];
    const float* Wih0 = (const float*)d_in[1];
    const float* Whh0 = (const float*)d_in[2];
    const float* bih0 = (const float*)d_in[3];
    const float* bhh0 = (const float*)d_in[4];
    const float* Wih1 = (const float*)d_in[5];
    const float* Whh1 = (const float*)d_in[6];
    const float* bih1 = (const float*)d_in[7];
    const float* bhh1 = (const float*)d_in[8];
    const float* Wlin = (const float*)d_in[9];
    const float* blin = (const float*)d_in[10];
    float* out = (float*)d_out;

    dim3 grid(Bsz / 8);   // 8 sequences per 256-thread block
    dim3 block(256);
    hipLaunchKernelGGL(lstm2_fused, grid, block, 0, stream,
                       x, Wih0, Whh0, bih0, bhh0,
                       Wih1, Whh1, bih1, bhh1, Wlin, blin, out);
}

// Round 2
// 1104.270 us; speedup vs baseline: 1.5884x; 1.5884x over previous
//
#include <hip/hip_runtime.h>

// 2-layer LSTM, B=2048, T=4096, IN=1, H=8, OUT=1, fp32.
//
// Lane layout (within each 32-lane group = one sequence; 2 seq/wave):
//   lane = L*16 + j*2 + p      L=layer, j=hidden unit (0..7), p=row-pair
// Lane (L,j,p) owns gate rows {2p, 2p+1} of unit j (PyTorch order i,f,g,o):
//   row A: g=2p   (p=0 -> i, p=1 -> g~ [tanh])
//   row B: g=2p+1 (p=0 -> f, p=1 -> o)
// Cross-lane traffic:
//   - gate pair-swap: quad_perm [1,0,3,2] DPP (lane^1, involutive)
//   - h all-gather: 15 independent xor ds_swizzles (one LDS round/step),
//     issued right after h; consumed only next iteration (layer pipeline:
//     iter t computes L0(t) and L1(t-1), both from prev-iter h state).
// Projection rides L0 lanes' spare dot-product slot (weights = W_lin).

constexpr int Bsz = 2048;
constexpr int Tsz = 4096;

template <int XORM>
__device__ __forceinline__ float swz(float v) {
    // ds_swizzle bit mode: src_lane = ((lane & 0x1f) | 0) ^ XORM  (pure xor)
    return __int_as_float(
        __builtin_amdgcn_ds_swizzle(__float_as_int(v), (XORM << 10) | 0x1f));
}

__device__ __forceinline__ float qswap(float v) {
    // quad_perm [1,0,3,2]: swap lane^1 within each quad. ctrl=0xB1.
    return __int_as_float(
        __builtin_amdgcn_mov_dpp(__float_as_int(v), 0xB1, 0xF, 0xF, true));
}

__global__ void __launch_bounds__(256) lstm2_swz(
    const float* __restrict__ x,      // [B, T]
    const float* __restrict__ Wih0,   // [32, 1]
    const float* __restrict__ Whh0,   // [32, 8]
    const float* __restrict__ bih0,   // [32]
    const float* __restrict__ bhh0,   // [32]
    const float* __restrict__ Wih1,   // [32, 8]
    const float* __restrict__ Whh1,   // [32, 8]
    const float* __restrict__ bih1,   // [32]
    const float* __restrict__ bhh1,   // [32]
    const float* __restrict__ Wlin,   // [1, 8]
    const float* __restrict__ blin,   // [1]
    float* __restrict__ out)          // [B, T]
{
    const int tid  = threadIdx.x;
    const int lane = tid & 31;
    const int p    = lane & 1;
    const int j    = (lane >> 1) & 7;
    const int Lyr  = (lane >> 4) & 1;
    const bool pb  = (p != 0);
    const int seq  = blockIdx.x * 8 + (tid >> 5);

    const int rA = p * 16 + j;        // gate row index of row A (g=2p)
    const int rB = p * 16 + 8 + j;    // gate row index of row B (g=2p+1)

    const float NL2E  = -1.4426950408889634f;   // -log2(e)
    const float N2L2E = -2.8853900817779268f;   // -2*log2(e)
    const float wsA = pb ? N2L2E : NL2E;        // row A: tanh needs 2x scale
    const float wsB = NL2E;                     // row B: always sigmoid
    const float sA  = pb ? 2.0f : 1.0f;         // tanh = 2*sig(2z)-1
    const float oA  = pb ? -1.0f : 0.0f;

    const float* __restrict__ Whh = Lyr ? Whh1 : Whh0;
    const float* __restrict__ bih = Lyr ? bih1 : bih0;
    const float* __restrict__ bhh = Lyr ? bhh1 : bhh0;

    // xor-permuted weight rows: slot s pairs with h[j^s]
    float wA[8], wB[8], vA[8], vB[8];
#pragma unroll
    for (int s = 0; s < 8; ++s) {
        const int k = j ^ s;
        wA[s] = Whh[rA * 8 + k] * wsA;
        wB[s] = Whh[rB * 8 + k] * wsB;
        if (Lyr) {   // L1: second dot = W_ih1 against other layer's h (h1)
            vA[s] = Wih1[rA * 8 + k] * wsA;
            vB[s] = Wih1[rB * 8 + k] * wsB;
        } else {     // L0: spare slot computes the projection (unscaled)
            vA[s] = Wlin[k];
            vB[s] = 0.0f;
        }
    }
    const float wxA   = Lyr ? 0.0f : Wih0[rA] * wsA;   // IN==1
    const float wxB   = Lyr ? 0.0f : Wih0[rB] * wsB;
    const float biasA = (bih[rA] + bhh[rA]) * wsA;
    const float biasB = (bih[rB] + bhh[rB]) * wsB;
    const float qA0   = Lyr ? 0.0f : blin[0];
    const float mL    = Lyr ? 1.0f : 0.0f;   // add second dot into z only on L1
    const float keep  = 1.0f - mL;

    const float* __restrict__ xp = x + (size_t)seq * Tsz;
    float* __restrict__ op       = out + (size_t)seq * Tsz;
    const bool lane0 = (lane == 0);

    float hA[8], hB[8];
#pragma unroll
    for (int s = 0; s < 8; ++s) { hA[s] = 0.0f; hB[s] = 0.0f; }
    float c = 0.0f, h = 0.0f, proj = 0.0f;

    auto cellstep = [&](float xt) {
        float zA = biasA, zB = biasB, pAcc = qA0, pBcc = 0.0f;
#pragma unroll
        for (int s = 0; s < 8; ++s) {
            zA   = fmaf(wA[s], hA[s], zA);
            zB   = fmaf(wB[s], hA[s], zB);
            pAcc = fmaf(vA[s], hB[s], pAcc);
            pBcc = fmaf(vB[s], hB[s], pBcc);
        }
        zA = fmaf(pAcc, mL, zA);      // L1: add ih-dot; L0: no-op (mL=0)
        zB = fmaf(pBcc, mL, zB);
        zA = fmaf(wxA, xt, zA);       // L0 input term; L1: wx=0
        zB = fmaf(wxB, xt, zB);
        // z pre-scaled by -log2e (or -2log2e): gate = rcp(1 + exp2(z))
        float aA = __builtin_amdgcn_rcpf(1.0f + __builtin_amdgcn_exp2f(zA));
        float gA = fmaf(aA, sA, oA);  // p=0: sigmoid(i); p=1: tanh(g~)
        float gB = __builtin_amdgcn_rcpf(1.0f + __builtin_amdgcn_exp2f(zB));
        float sgA = qswap(gA);        // partner's row-A gate
        float sgB = qswap(gB);        // partner's row-B gate
        float f = pb ? sgB : gB;
        float o = pb ? gB : sgB;
        c = fmaf(f, c, gA * sgA);     // gA*sgA == i*g~ on both p lanes
        float e  = __builtin_amdgcn_exp2f(c * N2L2E);
        float th = fmaf(2.0f, __builtin_amdgcn_rcpf(1.0f + e), -1.0f);
        h = o * th;
        proj = pAcc;                  // on L0 lanes: blin + Wlin . h2(t-2)
    };

    auto gather = [&]() {
        // one batch of independent xor-swizzles (single LDS round)
        hA[0] = h;                    // own-layer h[j]
        hA[1] = swz<2>(h);   hA[2] = swz<4>(h);   hA[3] = swz<6>(h);
        hA[4] = swz<8>(h);   hA[5] = swz<10>(h);  hA[6] = swz<12>(h);
        hA[7] = swz<14>(h);
        hB[0] = swz<16>(h);  hB[1] = swz<18>(h);  hB[2] = swz<20>(h);
        hB[3] = swz<22>(h);  hB[4] = swz<24>(h);  hB[5] = swz<26>(h);
        hB[6] = swz<28>(h);  hB[7] = swz<30>(h);
    };

    // ---- peel t=0: L0 computes h1(0) from x(0); L1 result discarded ----
    cellstep(xp[0]);
    h *= keep;   // h2(-1) = 0
    c *= keep;   // c2(-1) = 0
    gather();

    // ---- main loop: iter t computes L0(t) and L1(t-1) ----
    float xn1 = xp[1];
    float xn2 = xp[2];
    for (int t = 1; t <= Tsz + 1; ++t) {
        const float xt = xn1;
        xn1 = xn2;
        int ti = t + 2; ti = (ti < Tsz) ? ti : (Tsz - 1);
        xn2 = xp[ti];                 // prefetch distance 2

        cellstep(xt);
        if (t >= 2) {                 // proj(t-2) = Wlin . h2(t-2) + blin
            if (lane0) op[t - 2] = proj;
        }
        gather();
    }
}

extern "C" void kernel_launch(void* const* d_in, const int* in_sizes, int n_in,
                              void* d_out, int out_size, void* d_ws, size_t ws_size,
                              hipStream_t stream) {
    const float* x    = (const float*)d_in[0];
    const float* Wih0 = (const float*)d_in[1];
    const float* Whh0 = (const float*)d_in[2];
    const float* bih0 = (const float*)d_in[3];
    const float* bhh0 = (const float*)d_in[4];
    const float* Wih1 = (const float*)d_in[5];
    const float* Whh1 = (const float*)d_in[6];
    const float* bih1 = (const float*)d_in[7];
    const float* bhh1 = (const float*)d_in[8];
    const float* Wlin = (const float*)d_in[9];
    const float* blin = (const float*)d_in[10];
    float* out = (float*)d_out;

    dim3 grid(Bsz / 8);   // 8 sequences per 256-thread block (2 per wave)
    dim3 block(256);
    hipLaunchKernelGGL(lstm2_swz, grid, block, 0, stream,
                       x, Wih0, Whh0, bih0, bhh0,
                       Wih1, Whh1, bih1, bhh1, Wlin, blin, out);
}